// Round 9
// baseline (599.611 us; speedup 1.0000x reference)
//
#include <hip/hip_runtime.h>
#include <hip/hip_bf16.h>
#include <hip/hip_fp16.h>
#include <cstdint>

#define NEG (-1.0e30f)
#define INVLN2 1.44269504088896340736f
#define LN2    0.69314718055994530942f

typedef unsigned short u16;
typedef __attribute__((ext_vector_type(8))) short short8;
typedef __attribute__((ext_vector_type(4))) float f32x4;

typedef const __attribute__((address_space(1))) void cg_void;
typedef __attribute__((address_space(3))) void lds_void;

// dims
#define Bsz   32
#define Tlen  1000
#define Cdim  512
#define Vdim  2000
#define Udim  100
#define Mrows (Bsz * Tlen)   // 32000
#define Npad  2048
#define GROW  256            // G row stride (floats) = 1024 B
#define BROWS 1040           // padded G rows per b
#define KPAD  1024           // padded per-lane stream length (dwords)

// ws layout (bytes). G (34.1 MB) aliases a_bf+w_bf (dead after gemm).
// Gt (8.4 MB) aliases Z (dead after cr_stats).
#define WS_ABF 0u
#define WS_G   0u
#define WS_WBF 32768000u                    // a_bf: 32000*512*2
#define WS_Z   (WS_WBF + 2097152u)          // w_bf: 2048*512*2
#define WS_GT  WS_Z                         // Gt: 32*64*1024*4 = 8.39 MB
#define WS_ACC (WS_Z + 128000000u)          // accum: 2 floats

__device__ inline u16 f2bf(float x) {
  uint32_t u = __float_as_uint(x);
  uint32_t r = (u + 0x7fffu + ((u >> 16) & 1u)) >> 16;
  return (u16)r;
}
__device__ inline float bf2f(u16 u) {
  return __uint_as_float(((uint32_t)u) << 16);
}

__device__ inline float waveMax(float v) {
  #pragma unroll
  for (int o = 32; o > 0; o >>= 1) v = fmaxf(v, __shfl_down(v, o));
  return v;
}
__device__ inline float waveSum(float v) {
  #pragma unroll
  for (int o = 32; o > 0; o >>= 1) v += __shfl_down(v, o);
  return v;
}

// log-sum-exp in log2 space, minimized transcendental count.
__device__ inline float lse2_2(float a, float b) {
  float m = fmaxf(a, b);
  float d = fminf(a, b) - m;
  return m + log2f(1.0f + exp2f(d));
}
__device__ inline float lse3_2(float a, float b, float c) {
  float m = fmaxf(a, fmaxf(b, c));
  float x = __builtin_amdgcn_fmed3f(a, b, c) - m;
  float y = fminf(a, fminf(b, c)) - m;
  return m + log2f(1.0f + exp2f(x) + exp2f(y));
}

// shift value from lane-1 into this lane via DPP wave_shr:1 (VALU, no LDS).
__device__ inline float shiftup1(float x, float fill) {
  int r = __builtin_amdgcn_update_dpp(__float_as_int(fill), __float_as_int(x),
                                      0x138, 0xF, 0xF, false);
  return __int_as_float(r);
}

// unpack {fp16,fp16} dword -> float2
__device__ inline float2 up2(unsigned int dw) {
  union { unsigned int u; __half2 h; } cv; cv.u = dw;
  return __half22float2(cv.h);
}
__device__ inline unsigned int pk2(float x, float y) {
  union { unsigned int u; __half2 h; } cv;
  cv.h = __floats2half2_rn(x, y);
  return cv.u;
}

// ---------------- K1: fp32 -> bf16 conversion, vectorized ------------------
__global__ void convert_kernel(const float4* __restrict__ enc4, const float4* __restrict__ W4,
                               uint4* __restrict__ a4, uint4* __restrict__ w4,
                               float* __restrict__ accum) {
  int idx = blockIdx.x * blockDim.x + threadIdx.x;
  int stride = gridDim.x * blockDim.x;
  if (idx == 0) { accum[0] = 0.0f; accum[1] = 0.0f; }
  const int nA = Mrows * Cdim / 8;
  const int nW = Vdim * Cdim / 8;
  const int nWp = Npad * Cdim / 8;
  for (int i = idx; i < nA; i += stride) {
    float4 x = enc4[2 * i], y = enc4[2 * i + 1];
    uint4 o;
    o.x = (uint32_t)f2bf(x.x) | ((uint32_t)f2bf(x.y) << 16);
    o.y = (uint32_t)f2bf(x.z) | ((uint32_t)f2bf(x.w) << 16);
    o.z = (uint32_t)f2bf(y.x) | ((uint32_t)f2bf(y.y) << 16);
    o.w = (uint32_t)f2bf(y.z) | ((uint32_t)f2bf(y.w) << 16);
    a4[i] = o;
  }
  for (int i = idx; i < nWp; i += stride) {
    uint4 o = {0, 0, 0, 0};
    if (i < nW) {
      float4 x = W4[2 * i], y = W4[2 * i + 1];
      o.x = (uint32_t)f2bf(x.x) | ((uint32_t)f2bf(x.y) << 16);
      o.y = (uint32_t)f2bf(x.z) | ((uint32_t)f2bf(x.w) << 16);
      o.z = (uint32_t)f2bf(y.x) | ((uint32_t)f2bf(y.y) << 16);
      o.w = (uint32_t)f2bf(y.z) | ((uint32_t)f2bf(y.w) << 16);
    }
    w4[i] = o;
  }
}

// ---------------- K2: bf16 GEMM (A: 32000x512, W: 2048x512, C = A*W^T) -----
__global__ __launch_bounds__(256) void gemm_kernel(const u16* __restrict__ A,
                                                   const u16* __restrict__ Wb,
                                                   u16* __restrict__ Z) {
  __shared__ __attribute__((aligned(16))) u16 As[128 * 64];
  __shared__ __attribute__((aligned(16))) u16 Bs[128 * 64];
  const int tid = threadIdx.x;
  const int wave = tid >> 6;
  const int lane = tid & 63;
  const int nBase = blockIdx.x * 128;
  const int mBase = blockIdx.y * 128;
  const int m_lane = lane & 15;
  const int quad = lane >> 4;

  f32x4 acc[4][4];
  const f32x4 zero4 = {0.0f, 0.0f, 0.0f, 0.0f};
  #pragma unroll
  for (int i = 0; i < 4; ++i)
    #pragma unroll
    for (int j = 0; j < 4; ++j) acc[i][j] = zero4;

  for (int k0 = 0; k0 < Cdim; k0 += 64) {
    #pragma unroll
    for (int r = 0; r < 4; ++r) {
      int u = r * 256 + tid;
      int g = u >> 3;
      int q = (u & 7) ^ (g & 7);
      const u16* gpA = A + ((size_t)(mBase + g) << 9) + (k0 + (q << 3));
      __builtin_amdgcn_global_load_lds((cg_void*)gpA, (lds_void*)&As[(r * 4 + wave) * 512],
                                       16, 0, 0);
      const u16* gpB = Wb + ((size_t)(nBase + g) << 9) + (k0 + (q << 3));
      __builtin_amdgcn_global_load_lds((cg_void*)gpB, (lds_void*)&Bs[(r * 4 + wave) * 512],
                                       16, 0, 0);
    }
    __syncthreads();
    #pragma unroll
    for (int kk = 0; kk < 2; ++kk) {
      short8 af[4], bfv[4];
      #pragma unroll
      for (int mi = 0; mi < 4; ++mi) {
        int row = (wave >> 1) * 64 + mi * 16 + m_lane;
        int q = (kk * 4 + quad) ^ (row & 7);
        af[mi] = *(const short8*)&As[row * 64 + (q << 3)];
      }
      #pragma unroll
      for (int ni = 0; ni < 4; ++ni) {
        int col = (wave & 1) * 64 + ni * 16 + m_lane;
        int q = (kk * 4 + quad) ^ (col & 7);
        bfv[ni] = *(const short8*)&Bs[col * 64 + (q << 3)];
      }
      #pragma unroll
      for (int mi = 0; mi < 4; ++mi)
        #pragma unroll
        for (int ni = 0; ni < 4; ++ni)
          acc[mi][ni] = __builtin_amdgcn_mfma_f32_16x16x32_bf16(af[mi], bfv[ni],
                                                                acc[mi][ni], 0, 0, 0);
    }
    __syncthreads();
  }
  #pragma unroll
  for (int ni = 0; ni < 4; ++ni) {
    int col = nBase + (wave & 1) * 64 + ni * 16 + m_lane;
    if (col < Vdim) {
      #pragma unroll
      for (int mi = 0; mi < 4; ++mi) {
        int row0 = mBase + (wave >> 1) * 64 + mi * 16 + quad * 4;
        #pragma unroll
        for (int rg = 0; rg < 4; ++rg)
          Z[(size_t)(row0 + rg) * Vdim + col] = f2bf(acc[mi][ni][rg]);
      }
    }
  }
}

// ---------------- K3: fused softmax stats + CR loss + CTC gather -----------
__global__ __launch_bounds__(256) void cr_stats_kernel(const u16* __restrict__ Z,
                                                       const float* __restrict__ bias,
                                                       const int* __restrict__ lens,
                                                       const int* __restrict__ targets,
                                                       float* __restrict__ G,
                                                       float* __restrict__ accum) {
  int bp = blockIdx.x;   // 0..15
  int t = blockIdx.y;    // 0..999
  int tid = threadIdx.x;
  int wave = tid >> 6, lane = tid & 63;
  size_t r1 = (size_t)bp * Tlen + t;
  size_t r2 = r1 + (size_t)16 * Tlen;
  const u16* z1 = Z + r1 * Vdim;
  const u16* z2 = Z + r2 * Vdim;

  __shared__ float ls1[Vdim];
  __shared__ float ls2[Vdim];
  __shared__ float red[8];

  float v1[8], v2[8];
  float mx1 = NEG, mx2 = NEG;
  #pragma unroll
  for (int i = 0; i < 8; ++i) {
    int col = i * 256 + tid;
    if (col < Vdim) {
      float bb = bias[col];
      v1[i] = bf2f(z1[col]) + bb;
      v2[i] = bf2f(z2[col]) + bb;
      ls1[col] = v1[i];
      ls2[col] = v2[i];
      mx1 = fmaxf(mx1, v1[i]);
      mx2 = fmaxf(mx2, v2[i]);
    } else { v1[i] = NEG; v2[i] = NEG; }
  }
  float w1 = waveMax(mx1), w2 = waveMax(mx2);
  if (lane == 0) { red[wave] = w1; red[4 + wave] = w2; }
  __syncthreads();
  float M1 = fmaxf(fmaxf(red[0], red[1]), fmaxf(red[2], red[3]));
  float M2 = fmaxf(fmaxf(red[4], red[5]), fmaxf(red[6], red[7]));
  __syncthreads();
  float e1[8], e2[8];
  float s1 = 0.0f, s2 = 0.0f;
  #pragma unroll
  for (int i = 0; i < 8; ++i) {
    e1[i] = __expf(v1[i] - M1);
    e2[i] = __expf(v2[i] - M2);
    s1 += e1[i];
    s2 += e2[i];
  }
  s1 = waveSum(s1); s2 = waveSum(s2);
  if (lane == 0) { red[wave] = s1; red[4 + wave] = s2; }
  __syncthreads();
  float S1 = red[0] + red[1] + red[2] + red[3];
  float S2 = red[4] + red[5] + red[6] + red[7];
  float c1 = M1 + __logf(S1);
  float c2 = M2 + __logf(S2);
  float rS1 = 1.0f / S1, rS2 = 1.0f / S2;

  if (tid < 64) {
    int i1 = min(2 * tid, Udim - 1);
    int i3 = min(2 * tid + 1, Udim - 1);
    int t1a = targets[bp * Udim + i1];
    int t1b = targets[bp * Udim + i3];
    int t2a = targets[(bp + 16) * Udim + i1];
    int t2b = targets[(bp + 16) * Udim + i3];
    float4 g1 = {(ls1[t1a] - c1) * INVLN2, (ls1[t1b] - c1) * INVLN2,
                 (ls1[0] - c1) * INVLN2, 0.0f};
    float4 g2 = {(ls2[t2a] - c2) * INVLN2, (ls2[t2b] - c2) * INVLN2,
                 (ls2[0] - c2) * INVLN2, 0.0f};
    *(float4*)(G + ((size_t)bp * BROWS + t) * GROW + 4 * tid) = g1;
    *(float4*)(G + ((size_t)(bp + 16) * BROWS + t) * GROW + 4 * tid) = g2;
  }

  float f = 0.0f;
  #pragma unroll
  for (int i = 0; i < 8; ++i) {
    float p1 = e1[i] * rS1;
    float p2 = e2[i] * rS2;
    f += (p1 - p2) * (v1[i] - v2[i]);
  }
  __syncthreads();
  f = waveSum(f);
  if (lane == 0) red[wave] = f;
  __syncthreads();
  if (tid == 0 && t < lens[bp]) {
    atomicAdd(&accum[1], 0.5f * (red[0] + red[1] + red[2] + red[3]));
  }
}

// ---------------- K3b: transpose G rows -> per-lane fp16 streams -----------
// Gt[b][lane][k] (k=t-1, padded to 1024): dword = {fp16 lp(tgt[2l]),
// fp16 lp(tgt[2l+1])}; lane 56 carries {blank, blank} (its states >200 are
// dead). Per lane the scan reads 64 B contiguous per 16-step window.
__global__ __launch_bounds__(64) void transpose_kernel(const float* __restrict__ G,
                                                       unsigned int* __restrict__ Gt) {
  int b = blockIdx.x;       // 0..31
  int tile = blockIdx.y;    // 0..62 (k = tile*16 .. +15, t = k+1)
  int l = threadIdx.x;
  unsigned int d[16];
  #pragma unroll
  for (int i = 0; i < 16; ++i) {
    const float4 v = *(const float4*)(G + ((size_t)b * BROWS + tile * 16 + 1 + i) * GROW + 4 * l);
    d[i] = (l == 56) ? pk2(v.z, v.z) : pk2(v.x, v.y);
  }
  uint4* dst = (uint4*)(Gt + ((size_t)(b * 64 + l) * KPAD + tile * 16));
  dst[0] = make_uint4(d[0], d[1], d[2], d[3]);
  dst[1] = make_uint4(d[4], d[5], d[6], d[7]);
  dst[2] = make_uint4(d[8], d[9], d[10], d[11]);
  dst[3] = make_uint4(d[12], d[13], d[14], d[15]);
}

// ---------------- K4: CTC forward scan, one wave per sequence --------------
// Per-lane fp16 streams: a 16-step window = 4 dwordx4 per lane (contiguous
// 64 B) + 1 broadcast dwordx4 (lane 56's stream = blanks). Double-banked
// named registers; next-window loads issued before the 16 recurrence steps.
#define STEPX(j, CD, BD) {                                                   \
    float2 lp = up2(CD);                                                     \
    float lpBk = up2(BD).x;                                                  \
    float p3 = shiftup1(a3, NEG);                                            \
    float n0v = lse2_2(a0, p3) + lpBk;                                       \
    float n1v = lse3_2(a1, a0, skip1 ? p3 : NEG) + lp.x;                     \
    float n2v = lse2_2(a2, a1) + lpBk;                                       \
    float n3v = lse3_2(a3, a2, skip3 ? a1 : NEG) + lp.y;                     \
    bool act = (k0 + (j)) < lenm1;                                           \
    a0 = act ? n0v : a0; a1 = act ? n1v : a1;                                \
    a2 = act ? n2v : a2; a3 = act ? n3v : a3; }

__global__ __launch_bounds__(64, 1) void ctc_kernel(const unsigned int* __restrict__ Gt,
                                                    const float* __restrict__ G,
                                                    const int* __restrict__ targets,
                                                    const int* __restrict__ lens,
                                                    const int* __restrict__ tlens,
                                                    float* __restrict__ accum) {
  __shared__ float fin[256];
  int b = blockIdx.x;
  int lane = threadIdx.x;
  const int* tgt = targets + b * Udim;
  int i1 = min(2 * lane, Udim - 1);
  int i3 = min(2 * lane + 1, Udim - 1);
  int l1 = tgt[i1];
  int l3 = tgt[i3];
  int lm1 = tgt[min(max(2 * lane - 1, 0), Udim - 1)];
  bool skip1 = (lane >= 1) && (l1 != lm1);
  bool skip3 = (l3 != l1);
  int len = lens[b];
  int lenm1 = len - 1;
  int tl = tlens[b];

  // t=0 init (log2 space) from G row 0: lane0 float4 = {lp(tgt0),.., blank,..}
  const float4 v0 = *(const float4*)(G + (size_t)b * BROWS * GROW + 4 * lane);
  float a0 = (lane == 0) ? v0.z : NEG;
  float a1 = (lane == 0) ? v0.x : NEG;
  float a2 = NEG, a3 = NEG;

  const uint4* st = (const uint4*)Gt + (size_t)(b * 64 + lane) * (KPAD / 4);
  const uint4* sb = (const uint4*)Gt + (size_t)(b * 64 + 56) * (KPAD / 4);

  // prime window 0 (k = 0..15, i.e. t = 1..16)
  uint4 c0 = st[0], c1 = st[1], c2 = st[2], c3 = st[3];
  uint4 b0 = sb[0], b1 = sb[1], b2 = sb[2], b3 = sb[3];

  int nwin = (lenm1 + 15) >> 4;   // covers t = 1..len-1
  for (int w = 0; w < nwin; ++w) {
    int k0 = w << 4;
    // issue next window's loads (indices <= 255, within the 1024-dword pad)
    uint4 n0 = st[4 * w + 4], n1 = st[4 * w + 5], n2 = st[4 * w + 6], n3 = st[4 * w + 7];
    uint4 m0 = sb[4 * w + 4], m1 = sb[4 * w + 5], m2 = sb[4 * w + 6], m3 = sb[4 * w + 7];
    __builtin_amdgcn_sched_barrier(0);
    STEPX(0,  c0.x, b0.x)  STEPX(1,  c0.y, b0.y)
    STEPX(2,  c0.z, b0.z)  STEPX(3,  c0.w, b0.w)
    STEPX(4,  c1.x, b1.x)  STEPX(5,  c1.y, b1.y)
    STEPX(6,  c1.z, b1.z)  STEPX(7,  c1.w, b1.w)
    STEPX(8,  c2.x, b2.x)  STEPX(9,  c2.y, b2.y)
    STEPX(10, c2.z, b2.z)  STEPX(11, c2.w, b2.w)
    STEPX(12, c3.x, b3.x)  STEPX(13, c3.y, b3.y)
    STEPX(14, c3.z, b3.z)  STEPX(15, c3.w, b3.w)
    c0 = n0; c1 = n1; c2 = n2; c3 = n3;
    b0 = m0; b1 = m1; b2 = m2; b3 = m3;
  }

  fin[4 * lane + 0] = a0;
  fin[4 * lane + 1] = a1;
  fin[4 * lane + 2] = a2;
  fin[4 * lane + 3] = a3;
  __syncthreads();
  if (lane == 0) {
    int end = 2 * tl;
    float x = fin[end], y = fin[end - 1];
    float m = fmaxf(x, y);
    float loss = -LN2 * (m + log2f(exp2f(x - m) + exp2f(y - m)));
    atomicAdd(&accum[0], 0.5f * loss);
  }
}

// ---------------- K5: finalize to FP32 output ------------------------------
__global__ void finalize_kernel(const float* __restrict__ accum, float* __restrict__ out) {
  if (threadIdx.x == 0) {
    out[0] = accum[0];
    out[1] = accum[1];
  }
}

extern "C" void kernel_launch(void* const* d_in, const int* in_sizes, int n_in,
                              void* d_out, int out_size, void* d_ws, size_t ws_size,
                              hipStream_t stream) {
  const float* enc = (const float*)d_in[0];
  const float* W = (const float*)d_in[1];
  const float* bias = (const float*)d_in[2];
  const int* lens = (const int*)d_in[3];
  const int* targets = (const int*)d_in[4];
  const int* tlens = (const int*)d_in[5];

  char* ws = (char*)d_ws;
  u16* a_bf = (u16*)(ws + WS_ABF);
  u16* w_bf = (u16*)(ws + WS_WBF);
  u16* Zb   = (u16*)(ws + WS_Z);
  float* Gp  = (float*)(ws + WS_G);            // aliases a_bf+w_bf (dead after gemm)
  unsigned int* Gtp = (unsigned int*)(ws + WS_GT);  // aliases Z (dead after cr_stats)
  float* accum = (float*)(ws + WS_ACC);

  hipLaunchKernelGGL(convert_kernel, dim3(1024), dim3(256), 0, stream,
                     (const float4*)enc, (const float4*)W, (uint4*)a_bf, (uint4*)w_bf, accum);
  hipLaunchKernelGGL(gemm_kernel, dim3(16, 250), dim3(256), 0, stream,
                     a_bf, w_bf, Zb);
  hipLaunchKernelGGL(cr_stats_kernel, dim3(16, 1000), dim3(256), 0, stream,
                     Zb, bias, lens, targets, Gp, accum);
  hipLaunchKernelGGL(transpose_kernel, dim3(Bsz, 63), dim3(64), 0, stream,
                     Gp, Gtp);
  hipLaunchKernelGGL(ctc_kernel, dim3(Bsz), dim3(64), 0, stream,
                     Gtp, Gp, targets, lens, tlens, accum);
  hipLaunchKernelGGL(finalize_kernel, dim3(1), dim3(64), 0, stream,
                     accum, (float*)d_out);
}